// Round 1
// baseline (436.794 us; speedup 1.0000x reference)
//
#include <hip/hip_runtime.h>

#define EPROJS 1024
#define DUNITS 1024
#define AHEADS 4
#define DK 512
#define DV 512
#define CCH 128
#define BB 16
#define TT 2048

typedef __attribute__((ext_vector_type(8))) short bf16x8;
typedef __attribute__((ext_vector_type(4))) float f32x4;

static __device__ __forceinline__ short f2bf(float x) {
  unsigned u = __float_as_uint(x);
  unsigned r = u + 0x7fffu + ((u >> 16) & 1u);   // RNE to bf16 (inputs finite)
  return (short)(r >> 16);
}

static __device__ __forceinline__ float fast_tanh(float x) {
  float e2 = __expf(2.0f * x);
  return 1.0f - 2.0f / (e2 + 1.0f);   // safe at +-inf of e2
}

// ---------- f32 -> bf16 conversion (vector of 4) ----------
__global__ __launch_bounds__(256) void cvt_kernel(const float* __restrict__ in,
                                                  short* __restrict__ out, int n4) {
  int i = blockIdx.x * blockDim.x + threadIdx.x;
  if (i >= n4) return;
  float4 v = reinterpret_cast<const float4*>(in)[i];
  short4 o;
  o.x = f2bf(v.x); o.y = f2bf(v.y); o.z = f2bf(v.z); o.w = f2bf(v.w);
  reinterpret_cast<short4*>(out)[i] = o;
}

// ---------- filter prefix sums: S[h][tau][c], tau in [0, L] ----------
__global__ __launch_bounds__(128) void prefix_kernel(const float* __restrict__ w0,
                                                     const float* __restrict__ w1,
                                                     const float* __restrict__ w2,
                                                     const float* __restrict__ w3,
                                                     float* __restrict__ S) {
  int h = blockIdx.x, c = threadIdx.x;
  const float* wk = (h == 0) ? w0 : (h == 1) ? w1 : (h == 2) ? w2 : w3;
  int af = (100 * (h + 1)) >> 2;
  int L = 2 * af + 1;
  float* Sh = S + h * 202 * 128;
  float s = 0.f;
  Sh[c] = 0.f;
  for (int t = 0; t < L; ++t) { s += wk[c * L + t]; Sh[(t + 1) * 128 + c] = s; }
}

// ---------- Q[h][b][k] = dec_z[b] . Wq[h][k] + bq[h][k], one wave per output ----------
__global__ __launch_bounds__(256) void q_kernel(const float* __restrict__ dec,
                                                const float* __restrict__ Wq,
                                                const float* __restrict__ bq,
                                                float* __restrict__ Qb) {
  int wid = (blockIdx.x * blockDim.x + threadIdx.x) >> 6;
  int lane = threadIdx.x & 63;
  int k = wid & (DK - 1); int hb = wid >> 9; int b = hb & (BB - 1); int h = hb >> 4;
  const float4* d4 = reinterpret_cast<const float4*>(dec + b * DUNITS);
  const float4* w4 = reinterpret_cast<const float4*>(Wq + (size_t)(h * DK + k) * DUNITS);
  float s = 0.f;
#pragma unroll
  for (int j = 0; j < 4; ++j) {
    float4 a = d4[j * 64 + lane], w = w4[j * 64 + lane];
    s += a.x * w.x + a.y * w.y + a.z * w.z + a.w * w.w;
  }
#pragma unroll
  for (int off = 32; off; off >>= 1) s += __shfl_xor(s, off);
  if (lane == 0) Qb[wid] = s + bq[h * DK + k];
}

// ---------- fused e kernel: e[h][b][t] = sum_k tanh(enc.Wk^T + conv.Watt^T + Q) * g_w + g_b ----------
__global__ __launch_bounds__(512) void e_kernel(const float* __restrict__ enc,
                                                const short* __restrict__ Wkb,
                                                const short* __restrict__ Wattb,
                                                const float* __restrict__ S,
                                                const float* __restrict__ Qb,
                                                const float* __restrict__ gw,
                                                const float* __restrict__ gb,
                                                const int* __restrict__ lens,
                                                float* __restrict__ ebuf) {
  __shared__ short At[64][72];     // enc tile 64t x 64e, +8 bf16 pad (144B rows)
  __shared__ short Ac[64][136];    // conv tile 64t x 128c, +8 pad
  __shared__ float epart[8][64];

  int bid = blockIdx.x;
  int h = bid >> 9; int rem = bid & 511; int b = rem >> 5; int t0 = (rem & 31) << 6;
  int tid = threadIdx.x; int w = tid >> 6; int l = tid & 63;
  int lrow = l & 15, lhi = l >> 4;
  int len = lens[b];
  float invlen = 1.0f / (float)len;
  int af = (100 * (h + 1)) >> 2;

  // conv feature tile via prefix sums (valid for all t; masked later by softmax)
  const float* Sh = S + h * 202 * 128;
  for (int idx = tid; idx < 64 * 128; idx += 512) {
    int r = idx >> 7, c = idx & 127;
    int t = t0 + r;
    int lo = af - t; if (lo < 0) lo = 0;
    int hi = af - t + len - 1; if (hi > 2 * af) hi = 2 * af;
    float v = 0.f;
    if (hi >= lo) v = (Sh[(hi + 1) * 128 + c] - Sh[lo * 128 + c]) * invlen;
    Ac[r][c] = f2bf(v);
  }

  f32x4 acc[4][4] = {};
  const short* WkhB = Wkb + (size_t)h * DK * EPROJS;

  for (int e0 = 0; e0 < EPROJS; e0 += 64) {
    __syncthreads();
    {
      int r = tid >> 3, ch = tid & 7;
      const float* src = enc + ((size_t)(b * TT + t0 + r)) * EPROJS + e0 + ch * 8;
      float4 v0 = *reinterpret_cast<const float4*>(src);
      float4 v1 = *reinterpret_cast<const float4*>(src + 4);
      short4 o0, o1;
      o0.x = f2bf(v0.x); o0.y = f2bf(v0.y); o0.z = f2bf(v0.z); o0.w = f2bf(v0.w);
      o1.x = f2bf(v1.x); o1.y = f2bf(v1.y); o1.z = f2bf(v1.z); o1.w = f2bf(v1.w);
      *reinterpret_cast<short4*>(&At[r][ch * 8]) = o0;
      *reinterpret_cast<short4*>(&At[r][ch * 8 + 4]) = o1;
    }
    __syncthreads();
#pragma unroll
    for (int kk = 0; kk < 2; ++kk) {
      bf16x8 afr[4], bfr[4];
#pragma unroll
      for (int m = 0; m < 4; ++m)
        afr[m] = *reinterpret_cast<const bf16x8*>(&At[m * 16 + lrow][kk * 32 + lhi * 8]);
#pragma unroll
      for (int n = 0; n < 4; ++n) {
        int col = w * 64 + n * 16 + lrow;
        bfr[n] = *reinterpret_cast<const bf16x8*>(WkhB + (size_t)col * EPROJS + e0 + kk * 32 + lhi * 8);
      }
#pragma unroll
      for (int m = 0; m < 4; ++m)
#pragma unroll
        for (int n = 0; n < 4; ++n)
          acc[m][n] = __builtin_amdgcn_mfma_f32_16x16x32_bf16(afr[m], bfr[n], acc[m][n], 0, 0, 0);
    }
  }

  // conv channels as 4 extra K-steps
#pragma unroll
  for (int kk = 0; kk < 4; ++kk) {
    bf16x8 afr[4], bfr[4];
#pragma unroll
    for (int m = 0; m < 4; ++m)
      afr[m] = *reinterpret_cast<const bf16x8*>(&Ac[m * 16 + lrow][kk * 32 + lhi * 8]);
#pragma unroll
    for (int n = 0; n < 4; ++n) {
      int col = w * 64 + n * 16 + lrow;
      bfr[n] = *reinterpret_cast<const bf16x8*>(Wattb + (size_t)(h * DK + col) * CCH + kk * 32 + lhi * 8);
    }
#pragma unroll
    for (int m = 0; m < 4; ++m)
#pragma unroll
      for (int n = 0; n < 4; ++n)
        acc[m][n] = __builtin_amdgcn_mfma_f32_16x16x32_bf16(afr[m], bfr[n], acc[m][n], 0, 0, 0);
  }

  // epilogue: tanh(pre + Q) * g_w, reduce over k
  float part[4][4];
#pragma unroll
  for (int m = 0; m < 4; ++m)
#pragma unroll
    for (int r = 0; r < 4; ++r) part[m][r] = 0.f;

#pragma unroll
  for (int n = 0; n < 4; ++n) {
    int col = w * 64 + n * 16 + lrow;
    float q = Qb[(h * BB + b) * DK + col];
    float g = gw[h * DK + col];
#pragma unroll
    for (int m = 0; m < 4; ++m)
#pragma unroll
      for (int r = 0; r < 4; ++r)
        part[m][r] += fast_tanh(acc[m][n][r] + q) * g;
  }
#pragma unroll
  for (int off = 1; off < 16; off <<= 1)
#pragma unroll
    for (int m = 0; m < 4; ++m)
#pragma unroll
      for (int r = 0; r < 4; ++r) part[m][r] += __shfl_xor(part[m][r], off);

  if (lrow == 0) {
#pragma unroll
    for (int m = 0; m < 4; ++m)
#pragma unroll
      for (int r = 0; r < 4; ++r) epart[w][m * 16 + lhi * 4 + r] = part[m][r];
  }
  __syncthreads();
  if (tid < 64) {
    float s = gb[h];
#pragma unroll
    for (int ww = 0; ww < 8; ++ww) s += epart[ww][tid];
    ebuf[(size_t)(h * BB + b) * TT + t0 + tid] = s;
  }
}

// ---------- masked softmax over t; writes ws region of d_out ----------
__global__ __launch_bounds__(256) void softmax_kernel(const float* __restrict__ ebuf,
                                                      const int* __restrict__ lens,
                                                      float* __restrict__ wout) {
  int hb = blockIdx.x; int b = hb & (BB - 1);
  int tid = threadIdx.x;
  int len = lens[b];
  const float scaling = 0.04419417382415922f;  // 1/sqrt(512)
  const float* er = ebuf + (size_t)hb * TT;
  float vals[8];
  float mx = -1e30f;
#pragma unroll
  for (int j = 0; j < 8; ++j) {
    int t = j * 256 + tid;
    float v = (t < len) ? scaling * er[t] : -1e30f;
    vals[j] = v; mx = fmaxf(mx, v);
  }
  __shared__ float red[256];
  red[tid] = mx; __syncthreads();
  for (int s2 = 128; s2; s2 >>= 1) { if (tid < s2) red[tid] = fmaxf(red[tid], red[tid + s2]); __syncthreads(); }
  mx = red[0]; __syncthreads();
  float sum = 0.f;
#pragma unroll
  for (int j = 0; j < 8; ++j) {
    int t = j * 256 + tid;
    vals[j] = (t < len) ? __expf(vals[j] - mx) : 0.f;
    sum += vals[j];
  }
  red[tid] = sum; __syncthreads();
  for (int s2 = 128; s2; s2 >>= 1) { if (tid < s2) red[tid] += red[tid + s2]; __syncthreads(); }
  float inv = 1.f / red[0];
#pragma unroll
  for (int j = 0; j < 8; ++j)
    wout[(size_t)hb * TT + j * 256 + tid] = vals[j] * inv;
}

__global__ __launch_bounds__(256) void zero_kernel(float* __restrict__ p, int n) {
  int i = blockIdx.x * blockDim.x + threadIdx.x;
  if (i < n) p[i] = 0.f;
}

// ---------- ctx[h][b][e] = sum_t w[h][b][t] * enc[b][t][e] ; enc read exactly once ----------
__global__ __launch_bounds__(256) void ctx_kernel(const float* __restrict__ enc,
                                                  const float* __restrict__ wout,
                                                  float* __restrict__ ctx) {
  int bid = blockIdx.x;                      // B * 4 * 8 = 512
  int tc = bid & 7; int ec = (bid >> 3) & 3; int b = bid >> 5;
  int tid = threadIdx.x;
  int ecol = ec * 256 + tid;
  int t0 = tc * 256;
  __shared__ float wls[4][256];
#pragma unroll
  for (int h = 0; h < 4; ++h) wls[h][tid] = wout[(size_t)(h * BB + b) * TT + t0 + tid];
  __syncthreads();
  float a0 = 0.f, a1 = 0.f, a2 = 0.f, a3 = 0.f;
  const float* ep = enc + ((size_t)(b * TT + t0)) * EPROJS + ecol;
  for (int t2 = 0; t2 < 256; ++t2) {
    float v = ep[(size_t)t2 * EPROJS];
    a0 += wls[0][t2] * v; a1 += wls[1][t2] * v; a2 += wls[2][t2] * v; a3 += wls[3][t2] * v;
  }
  atomicAdd(&ctx[(0 * BB + b) * EPROJS + ecol], a0);
  atomicAdd(&ctx[(1 * BB + b) * EPROJS + ecol], a1);
  atomicAdd(&ctx[(2 * BB + b) * EPROJS + ecol], a2);
  atomicAdd(&ctx[(3 * BB + b) * EPROJS + ecol], a3);
}

// ---------- cv[b][h*512+v] = ctx[h][b] . Wv[h][v] ----------
__global__ __launch_bounds__(256) void cv_kernel(const float* __restrict__ ctx,
                                                 const float* __restrict__ Wv,
                                                 float* __restrict__ cvb) {
  int wid = (blockIdx.x * blockDim.x + threadIdx.x) >> 6;
  int lane = threadIdx.x & 63;
  int v = wid & (DV - 1); int hb = wid >> 9; int b = hb & (BB - 1); int h = hb >> 4;
  const float4* c4 = reinterpret_cast<const float4*>(ctx + (size_t)(h * BB + b) * EPROJS);
  const float4* w4 = reinterpret_cast<const float4*>(Wv + (size_t)(h * DV + v) * EPROJS);
  float s = 0.f;
#pragma unroll
  for (int j = 0; j < 4; ++j) {
    float4 a = c4[j * 64 + lane], ww = w4[j * 64 + lane];
    s += a.x * ww.x + a.y * ww.y + a.z * ww.z + a.w * ww.w;
  }
#pragma unroll
  for (int off = 32; off; off >>= 1) s += __shfl_xor(s, off);
  if (lane == 0) cvb[b * 2048 + h * DV + v] = s;
}

// ---------- c[b][p] = cv[b] . Wo[p] ----------
__global__ __launch_bounds__(256) void out_kernel(const float* __restrict__ cvb,
                                                  const float* __restrict__ Wo,
                                                  float* __restrict__ outc) {
  int wid = (blockIdx.x * blockDim.x + threadIdx.x) >> 6;
  int lane = threadIdx.x & 63;
  int p = wid & 1023; int b = wid >> 10;
  const float4* a4 = reinterpret_cast<const float4*>(cvb + (size_t)b * 2048);
  const float4* w4 = reinterpret_cast<const float4*>(Wo + (size_t)p * 2048);
  float s = 0.f;
#pragma unroll
  for (int j = 0; j < 8; ++j) {
    float4 a = a4[j * 64 + lane], ww = w4[j * 64 + lane];
    s += a.x * ww.x + a.y * ww.y + a.z * ww.z + a.w * ww.w;
  }
#pragma unroll
  for (int off = 32; off; off >>= 1) s += __shfl_xor(s, off);
  if (lane == 0) outc[b * 1024 + p] = s;
}

extern "C" void kernel_launch(void* const* d_in, const int* in_sizes, int n_in,
                              void* d_out, int out_size, void* d_ws, size_t ws_size,
                              hipStream_t stream) {
  const float* enc  = (const float*)d_in[0];
  const int*   lens = (const int*)d_in[1];
  const float* dec  = (const float*)d_in[2];
  const float* Wq   = (const float*)d_in[3];
  const float* bq   = (const float*)d_in[4];
  const float* Wk   = (const float*)d_in[5];
  const float* Wv   = (const float*)d_in[6];
  const float* gw   = (const float*)d_in[7];
  const float* gb   = (const float*)d_in[8];
  const float* Watt = (const float*)d_in[9];
  const float* cw0  = (const float*)d_in[10];
  const float* cw1  = (const float*)d_in[11];
  const float* cw2  = (const float*)d_in[12];
  const float* cw3  = (const float*)d_in[13];
  const float* Wo   = (const float*)d_in[14];
  float* out = (float*)d_out;

  char* ws = (char*)d_ws;
  short* Wkb   = (short*)(ws);                 // 4 MiB
  short* Wattb = (short*)(ws + 4194304);       // 512 KiB
  float* S     = (float*)(ws + 4718592);       // 404 KiB
  float* Qb    = (float*)(ws + 5132288);       // 128 KiB
  float* ebuf  = (float*)(ws + 5263360);       // 512 KiB
  float* ctx   = (float*)(ws + 5787648);       // 256 KiB
  float* cvb   = (float*)(ws + 6049792);       // 128 KiB

  float* wsout = out + 16384;                  // ws output region (4,16,2048)

  cvt_kernel<<<2048, 256, 0, stream>>>(Wk, Wkb, 524288);
  cvt_kernel<<<256, 256, 0, stream>>>(Watt, Wattb, 65536);
  prefix_kernel<<<4, 128, 0, stream>>>(cw0, cw1, cw2, cw3, S);
  q_kernel<<<8192, 256, 0, stream>>>(dec, Wq, bq, Qb);
  zero_kernel<<<256, 256, 0, stream>>>(ctx, 65536);
  e_kernel<<<2048, 512, 0, stream>>>(enc, Wkb, Wattb, S, Qb, gw, gb, lens, ebuf);
  softmax_kernel<<<64, 256, 0, stream>>>(ebuf, lens, wsout);
  ctx_kernel<<<512, 256, 0, stream>>>(enc, wsout, ctx);
  cv_kernel<<<8192, 256, 0, stream>>>(ctx, Wv, cvb);
  out_kernel<<<4096, 256, 0, stream>>>(cvb, Wo, out);
}